// Round 9
// baseline (61.944 us; speedup 1.0000x reference)
//
#include <hip/hip_runtime.h>
#include <math.h>

// Problem constants (from reference)
#define B_    64
#define C_    8
#define T_    2048
#define K_    16
#define NF_   9
#define FEAT_ 144   // C_*NF_*2
#define MLP_  16
#define H1_   64
#define H2_   32
#define EFF_  60
#define W_    1988  // T_-EFF_
#define NCHK_ 32    // w-chunks of 64
#define PI_F  3.14159265358979323846f
#define L2E_  1.44269504088896340736f
// LDS padded strides (floats): 4 sub-groups hit disjoint bank quads (verified mod-32)
#define SPW   36
#define S1    20
#define S2    36

typedef float v2f __attribute__((ext_vector_type(2)));
__device__ __forceinline__ v2f pkfma(v2f a, v2f b, v2f c) {  // -> v_pk_fma_f32
  return __builtin_elementwise_fma(a, b, c);
}
__device__ __forceinline__ v2f lo2(float4 a) { v2f r; r.x = a.x; r.y = a.y; return r; }
__device__ __forceinline__ v2f hi2(float4 a) { v2f r; r.x = a.z; r.y = a.w; return r; }

// Twiddles: angle(t) = 2*pi*t/16; f[n] = sum win[k]*exp(-i*2*pi*n*k/16)
constexpr float COS16[16] = {
   1.0f,  0.92387953251128674f,  0.70710678118654752f,  0.38268343236508977f,
   0.0f, -0.38268343236508977f, -0.70710678118654752f, -0.92387953251128674f,
  -1.0f, -0.92387953251128674f, -0.70710678118654752f, -0.38268343236508977f,
   0.0f,  0.38268343236508977f,  0.70710678118654752f,  0.92387953251128674f };
constexpr float SIN16F[16] = {
   0.0f,  0.38268343236508977f,  0.70710678118654752f,  0.92387953251128674f,
   1.0f,  0.92387953251128674f,  0.70710678118654752f,  0.38268343236508977f,
   0.0f, -0.38268343236508977f, -0.70710678118654752f, -0.92387953251128674f,
  -1.0f, -0.92387953251128674f, -0.70710678118654752f, -0.38268343236508977f };

// ---- fast device math (hw transcendentals) ----
__device__ __forceinline__ float fast_log1p(float s) {
  return __builtin_amdgcn_logf(1.0f + s) * 0.69314718055994531f;
}
__device__ __forceinline__ float atanpi_poly(float r) {
  const float s2 = r * r;
  float p = -0.0037310f;
  p = fmaf(p, s2,  0.0167600f);
  p = fmaf(p, s2, -0.0370617f);
  p = fmaf(p, s2,  0.0616068f);
  p = fmaf(p, s2, -0.10587734f);
  p = fmaf(p, s2,  0.31830265f);
  return r * p;
}
__device__ __forceinline__ float atan2pi_fast(float im, float re) {
  const float ax = fabsf(re), ay = fabsf(im);
  const float mx = fmaxf(ax, ay), mn = fminf(ax, ay);
  const float r = mn * __builtin_amdgcn_rcpf(fmaxf(mx, 1e-37f));
  float t = atanpi_poly(r);
  t = (ay > ax) ? 0.5f - t : t;
  t = (__float_as_uint(re) & 0x80000000u) ? 1.0f - t : t;  // signbit(re), handles -0
  return copysignf(t, im);                                  // im=+0 keeps +pi convention
}
__device__ __forceinline__ float fast_tanh(float z) {
  const float az = fabsf(z);
  const float e = __builtin_amdgcn_exp2f(-2.8853900817779268f * az);  // exp(-2|z|)
  const float th = fmaf(-2.0f, e * __builtin_amdgcn_rcpf(1.0f + e), 1.0f);
  return copysignf(th, z);
}

// ---------------- Kernel: everything fused; 4 sub-lanes per w, shuffle combines ----------------
__global__ __launch_bounds__(256) void tcn_all(
    const float* __restrict__ x,
    const float* __restrict__ pw, const float* __restrict__ proj_b,
    const float* __restrict__ w1, const float* __restrict__ b1,
    const float* __restrict__ w2, const float* __restrict__ b2,
    const float* __restrict__ out_w, const float* __restrict__ out_b,
    const float* __restrict__ agg, float* __restrict__ partials) {
  __shared__ __align__(16) float PWl[72 * SPW];   // row r=c*9+n: [mag16 | ph16]
  __shared__ __align__(16) float W1p[H1_ * S1];
  __shared__ __align__(16) float W2p[H1_ * S2];
  __shared__ float B1s[H1_], B2s[H2_], OWs[H2_];
  __shared__ float red[4];

  const int tid = threadIdx.x;
  // ---- staging, transposing directly from the original layouts ----
  for (int idx = tid; idx < 72 * 32; idx += 256) {
    const int r = idx >> 5, j32 = idx & 31, e = j32 >> 4, j = j32 & 15;
    PWl[r * SPW + j32] = pw[j * FEAT_ + r * 2 + e];       // pw[j][f], f = 2r+e
  }
  for (int idx = tid; idx < H1_ * MLP_; idx += 256) {
    const int i = idx >> 4, j = idx & 15;
    W1p[i * S1 + j] = w1[idx];
  }
  for (int idx = tid; idx < H1_ * H2_; idx += 256) {
    const int i = idx >> 5, m = idx & 31;
    W2p[i * S2 + m] = w2[m * H1_ + i];                    // w2[m][i]
  }
  if (tid < H1_) B1s[tid] = b1[tid];
  if (tid < H2_) { B2s[tid] = b2[tid]; OWs[tid] = out_w[tid]; }

  // ---- softmax denominator (no max-sub: agg ~ N(0,0.1), exp well-conditioned) ----
  float se = 0.f;
  for (int i = tid; i < W_; i += 256) se += __builtin_amdgcn_exp2f(agg[i] * L2E_);
  #pragma unroll
  for (int s = 1; s < 64; s <<= 1) se += __shfl_xor(se, s, 64);
  if ((tid & 63) == 0) red[tid >> 6] = se;
  __syncthreads();   // the only barrier
  const float inv = 1.0f / ((red[0] + red[1]) + (red[2] + red[3]));

  const int lane = tid & 63;
  const int wave = tid >> 6;
  const int wloc = lane & 15;
  const int sub  = lane >> 4;
  const int b     = blockIdx.y;
  const int chunk = blockIdx.x;
  const int w  = chunk * 64 + wave * 16 + wloc;
  const int wl = (w < W_) ? w : (W_ - 1);   // clamp loads; mask at the end

  // ---- stage 1: DFT + feature + proj partial for channels 2sub, 2sub+1 ----
  v2f pacc2[8];
  #pragma unroll
  for (int q = 0; q < 8; q++) pacc2[q] = (v2f){0.f, 0.f};

  #pragma unroll
  for (int cc = 0; cc < 2; cc++) {
    const int c = sub * 2 + cc;
    const float* xc = x + ((size_t)b * C_ + c) * T_ + wl;
    float win[K_];
    #pragma unroll
    for (int k = 0; k < K_; k++) win[k] = xc[k * 4];
    float ae[8], bo[8];
    #pragma unroll
    for (int k = 0; k < 8; k++) { ae[k] = win[k] + win[k+8]; bo[k] = win[k] - win[k+8]; }

    // n = 0, 8: im == +0 exactly -> mag = log1p(|re|), ph = signbit(re)
    {
      const float r0 = ((ae[0]+ae[1])+(ae[2]+ae[3]))+((ae[4]+ae[5])+(ae[6]+ae[7]));
      const float r8 = ((ae[0]-ae[1])+(ae[2]-ae[3]))+((ae[4]-ae[5])+(ae[6]-ae[7]));
      const float mag0 = fast_log1p(fabsf(r0));
      const float mag8 = fast_log1p(fabsf(r8));
      const float ph0 = (__float_as_uint(r0) >> 31) ? 1.f : 0.f;
      const float ph8 = (__float_as_uint(r8) >> 31) ? 1.f : 0.f;
      const float4* rv0 = reinterpret_cast<const float4*>(&PWl[(c * NF_ + 0) * SPW]);
      const float4* rv8 = reinterpret_cast<const float4*>(&PWl[(c * NF_ + 8) * SPW]);
      const v2f mm0 = {mag0, mag0}, pp0 = {ph0, ph0};
      const v2f mm8 = {mag8, mag8}, pp8 = {ph8, ph8};
      #pragma unroll
      for (int q = 0; q < 4; q++) {
        const float4 a0 = rv0[q], b0 = rv0[q + 4];
        const float4 a8 = rv8[q], b8 = rv8[q + 4];
        pacc2[2*q]   = pkfma(mm0, lo2(a0), pkfma(pp0, lo2(b0), pacc2[2*q]));
        pacc2[2*q+1] = pkfma(mm0, hi2(a0), pkfma(pp0, hi2(b0), pacc2[2*q+1]));
        pacc2[2*q]   = pkfma(mm8, lo2(a8), pkfma(pp8, lo2(b8), pacc2[2*q]));
        pacc2[2*q+1] = pkfma(mm8, hi2(a8), pkfma(pp8, hi2(b8), pacc2[2*q+1]));
      }
    }

    // n = 1..7: full twiddles
    #pragma unroll
    for (int n = 1; n < 8; n++) {
      float re = 0.f, im = 0.f;
      #pragma unroll
      for (int k = 0; k < 8; k++) {
        const float v = (n & 1) ? bo[k] : ae[k];
        const int t = (n * k) & 15;
        re = fmaf(v,  COS16[t],  re);
        im = fmaf(v, -SIN16F[t], im);
      }
      const float s   = __builtin_amdgcn_sqrtf(fmaf(re, re, im * im));
      const float mag = fast_log1p(s);
      const float ph  = atan2pi_fast(im, re);
      const float4* rmv = reinterpret_cast<const float4*>(&PWl[(c * NF_ + n) * SPW]);
      const v2f mm = {mag, mag}, pp = {ph, ph};
      #pragma unroll
      for (int q = 0; q < 4; q++) {
        const float4 a  = rmv[q];       // mag weights
        const float4 bb = rmv[q + 4];   // ph weights
        pacc2[2*q]   = pkfma(mm, lo2(a), pkfma(pp, lo2(bb), pacc2[2*q]));
        pacc2[2*q+1] = pkfma(mm, hi2(a), pkfma(pp, hi2(bb), pacc2[2*q+1]));
      }
    }
  }

  // ---- combine pacc across subs (butterfly over lane bits 4,5) ----
  float* pf = reinterpret_cast<float*>(pacc2);
  #pragma unroll
  for (int j = 0; j < MLP_; j++) {
    pf[j] += __shfl_xor(pf[j], 16, 64);
    pf[j] += __shfl_xor(pf[j], 32, 64);
  }
  v2f p2[8];
  #pragma unroll
  for (int q = 0; q < 8; q++) {
    p2[q].x = fast_tanh(pf[2*q]   + proj_b[2*q])   * PI_F;
    p2[q].y = fast_tanh(pf[2*q+1] + proj_b[2*q+1]) * PI_F;
  }

  // ---- MLP tail: 16 rows per sub (i = sub + 4*ii) ----
  v2f h2a2[16];
  #pragma unroll
  for (int q = 0; q < 16; q++) h2a2[q] = (v2f){0.f, 0.f};
  #pragma unroll 4
  for (int ii = 0; ii < 16; ii++) {
    const int i = sub + ii * 4;
    const float4* r1 = reinterpret_cast<const float4*>(&W1p[i * S1]);
    v2f acc2 = {0.f, 0.f};
    #pragma unroll
    for (int q = 0; q < 4; q++) {
      const float4 a = r1[q];
      acc2 = pkfma(p2[2*q],   lo2(a), acc2);
      acc2 = pkfma(p2[2*q+1], hi2(a), acc2);
    }
    const float h1v = fmaxf(acc2.x + acc2.y + B1s[i], 0.f);
    const v2f hh = {h1v, h1v};
    const float4* r2 = reinterpret_cast<const float4*>(&W2p[i * S2]);
    #pragma unroll
    for (int q = 0; q < 8; q++) {
      const float4 a = r2[q];
      h2a2[2*q]   = pkfma(hh, lo2(a), h2a2[2*q]);
      h2a2[2*q+1] = pkfma(hh, hi2(a), h2a2[2*q+1]);
    }
  }
  // ---- combine h2a across subs ----
  float* hf = reinterpret_cast<float*>(h2a2);
  #pragma unroll
  for (int m = 0; m < H2_; m++) {
    hf[m] += __shfl_xor(hf[m], 16, 64);
    hf[m] += __shfl_xor(hf[m], 32, 64);
  }

  // ---- head split across subs: each sub does m in [8*sub, 8*sub+8), then combine ----
  v2f o2 = {0.f, 0.f};
  #pragma unroll
  for (int t = 0; t < 4; t++) {
    const int pm = sub * 4 + t;                 // pair index (m = 2*pm, 2*pm+1)
    const v2f h = h2a2[pm];
    v2f r;
    r.x = fmaxf(h.x + B2s[2*pm],     0.f);
    r.y = fmaxf(h.y + B2s[2*pm + 1], 0.f);
    const v2f ow = {OWs[2*pm], OWs[2*pm + 1]};
    o2 = pkfma(r, ow, o2);
  }
  float o = o2.x + o2.y;
  o += __shfl_xor(o, 16, 64);
  o += __shfl_xor(o, 32, 64);
  o += out_b[0];

  const float wv = __builtin_amdgcn_exp2f(agg[wl] * L2E_) * inv;
  float val = (sub == 0 && w < W_) ? o * wv : 0.f;
  // reduce the 16 sub0 lanes (bits 0-3); lanes 16+ mix garbage among themselves only
  #pragma unroll
  for (int s = 1; s < 16; s <<= 1) val += __shfl_xor(val, s, 64);
  if (lane == 0) partials[(b * NCHK_ + chunk) * 4 + wave] = val;
}

// ---------------- finalize: fixed-order sum of 128 partials per b ----------------
__global__ void finalize_kernel(const float* __restrict__ partials, float* __restrict__ out) {
  const int b = threadIdx.x;
  if (b < B_) {
    float s = 0.f;
    #pragma unroll 4
    for (int c = 0; c < NCHK_ * 4; c++) s += partials[b * NCHK_ * 4 + c];
    out[b] = s;
  }
}

extern "C" void kernel_launch(void* const* d_in, const int* in_sizes, int n_in,
                              void* d_out, int out_size, void* d_ws, size_t ws_size,
                              hipStream_t stream) {
  const float* x      = (const float*)d_in[0];
  const float* proj_w = (const float*)d_in[1];
  const float* proj_b = (const float*)d_in[2];
  const float* w1     = (const float*)d_in[3];
  const float* b1     = (const float*)d_in[4];
  const float* w2     = (const float*)d_in[5];
  const float* b2     = (const float*)d_in[6];
  const float* out_w  = (const float*)d_in[7];
  const float* out_b  = (const float*)d_in[8];
  const float* agg_w  = (const float*)d_in[9];

  float* partials = (float*)d_ws;   // B_*NCHK_*4 = 8192 floats, all written each launch

  tcn_all<<<dim3(NCHK_, B_), 256, 0, stream>>>(x, proj_w, proj_b, w1, b1, w2, b2,
                                               out_w, out_b, agg_w, partials);
  finalize_kernel<<<1, 64, 0, stream>>>(partials, (float*)d_out);
}